// Round 2
// baseline (385.458 us; speedup 1.0000x reference)
//
#include <hip/hip_runtime.h>
#include <hip/hip_bf16.h>
#include <cstdint>

// Problem constants: B=4, N=1024, F=1024, H=16, D=64, S=2N=2048.
typedef __hip_bfloat16 bf16;
typedef __attribute__((ext_vector_type(8))) short short8;   // 8 x bf16 (4 VGPRs)
typedef __attribute__((ext_vector_type(4))) float f32x4;
typedef __attribute__((ext_vector_type(2))) unsigned int uint2v;

#define MFMA16(a, b, c) __builtin_amdgcn_mfma_f32_16x16x32_bf16((a), (b), (c), 0, 0, 0)

__device__ __forceinline__ void gl2lds16(const void* g, void* l) {
  // async global->LDS, 16B/lane; LDS dest = wave-uniform base + lane*16
  __builtin_amdgcn_global_load_lds(
      (const __attribute__((address_space(1))) unsigned int*)g,
      (__attribute__((address_space(3))) unsigned int*)l,
      16, 0, 0);
}

// pack two f32 -> bf16x2, round-half-up (3 VALU ops: add, add, v_perm)
__device__ __forceinline__ unsigned int pkbf(float a, float b) {
  const unsigned int ua = __builtin_bit_cast(unsigned int, a) + 0x8000u;
  const unsigned int ub = __builtin_bit_cast(unsigned int, b) + 0x8000u;
  return __builtin_amdgcn_perm(ub, ua, 0x07060302u);  // {hi16(ub), hi16(ua)}
}

// Collect-swap across lane bit 5: r[0] = values from lanes bit5==0 of {a,b}
// (lane bit5 encodes source reg), r[1] = values from lanes bit5==1.
__device__ __forceinline__ uint2v plswap32(unsigned a, unsigned b) {
#if __has_builtin(__builtin_amdgcn_permlane32_swap)
  return __builtin_amdgcn_permlane32_swap(a, b, false, false);
#else
  const unsigned ax = __shfl_xor((int)a, 32), bx = __shfl_xor((int)b, 32);
  const bool hi = (threadIdx.x & 32) != 0;
  uint2v r;
  r[0] = hi ? bx : a;
  r[1] = hi ? b : ax;
  return r;
#endif
}

// Collect-swap across lane bit 4 (16-lane rows), same collect semantics.
__device__ __forceinline__ uint2v plswap16(unsigned a, unsigned b) {
#if __has_builtin(__builtin_amdgcn_permlane16_swap)
  return __builtin_amdgcn_permlane16_swap(a, b, false, false);
#else
  const unsigned ax = __shfl_xor((int)a, 16), bx = __shfl_xor((int)b, 16);
  const bool hi = (threadIdx.x & 16) != 0;
  uint2v r;
  r[0] = hi ? bx : a;
  r[1] = hi ? b : ax;
  return r;
#endif
}

// ---------------------------------------------------------------------------
// C[M,N] = A[M,K] @ Bt[N,K]^T + bias   (all bf16 in, fp32 accum)
// 128x128 tile, BK=32, 256 threads (4 waves in 2x2), 16x16x32 bf16 MFMA.
// ---------------------------------------------------------------------------
template <int WRITE_BF16>
__global__ __launch_bounds__(256) void gemm_bt(
    const bf16* __restrict__ A, const bf16* __restrict__ Bt,
    const float* __restrict__ bias, bf16* __restrict__ outb,
    float* __restrict__ outf, int M, int N, int K) {
  __shared__ bf16 sA[128 * 32];
  __shared__ bf16 sB[128 * 32];
  const int tid = threadIdx.x, w = tid >> 6, lane = tid & 63;
  const int n16 = lane & 15, quad = lane >> 4;
  const int mBase = blockIdx.y * 128, nBase = blockIdx.x * 128;
  const int wr = w >> 1, wc = w & 1;  // wave covers rows wr*64.., cols wc*64..

  f32x4 acc[4][4];
#pragma unroll
  for (int mi = 0; mi < 4; mi++)
#pragma unroll
    for (int ni = 0; ni < 4; ni++) acc[mi][ni] = (f32x4){0.f, 0.f, 0.f, 0.f};

  for (int k0 = 0; k0 < K; k0 += 32) {
    __syncthreads();  // previous iteration's frag reads must finish
#pragma unroll
    for (int i = 0; i < 2; i++) {
      const int f = (i * 256 + w * 64 + lane) * 8;  // element in 128x32 tile
      const int row = f >> 5, col = f & 31;
      bf16* ldsbase_a = sA + (i * 256 + w * 64) * 8;  // wave-uniform
      bf16* ldsbase_b = sB + (i * 256 + w * 64) * 8;
      gl2lds16(A + (size_t)(mBase + row) * K + k0 + col, ldsbase_a);
      gl2lds16(Bt + (size_t)(nBase + row) * K + k0 + col, ldsbase_b);
    }
    __syncthreads();  // drains vmcnt (global_load_lds) + makes LDS visible

    short8 af[4], bfg[4];
#pragma unroll
    for (int t = 0; t < 4; t++) {
      af[t] = *(const short8*)(sA + (wr * 64 + t * 16 + n16) * 32 + quad * 8);
      bfg[t] = *(const short8*)(sB + (wc * 64 + t * 16 + n16) * 32 + quad * 8);
    }
#pragma unroll
    for (int mi = 0; mi < 4; mi++)
#pragma unroll
      for (int ni = 0; ni < 4; ni++)
        acc[mi][ni] = MFMA16(af[mi], bfg[ni], acc[mi][ni]);
  }

  // Epilogue. C/D layout: col = lane&15, row = quad*4 + reg  [verified m89/m91]
#pragma unroll
  for (int mi = 0; mi < 4; mi++)
#pragma unroll
    for (int ni = 0; ni < 4; ni++)
#pragma unroll
      for (int r = 0; r < 4; r++) {
        const int row = mBase + wr * 64 + mi * 16 + quad * 4 + r;
        const int col = nBase + wc * 64 + ni * 16 + n16;
        const float v = acc[mi][ni][r] + bias[col];
        if (WRITE_BF16)
          outb[(size_t)row * N + col] = __float2bfloat16(v);
        else
          outf[(size_t)row * N + col] = v;
      }
}

// ---------------------------------------------------------------------------
// Flash attention v6: sPT eliminated. P^T is re-laid-out from the S^T fragment
// (key=kt4*16+quad*4+r, col q=n16) into the PV B-fragment (key=kc*32+quad*8+j,
// same n16) entirely in registers via a {bit5, bit4, reg-index} rotation:
//   swap1 (permlane32_swap pairs (kt4=2kc, 2kc+1)): reg kt4&1 -> lane bit5
//   swap2 (permlane16_swap pairs (q1=0, q1=1)):     lane bit5 -> bit4, bit4 -> reg
// LDS: 53248 -> 34816 B  => 4 blocks/CU (16 waves) instead of 3.
// K-loop processed per-kc (two 32-key chunks) to halve st/pb register liveness
// and stay under the 128-VGPR bound required for 16 waves/CU.
// Epilogue transpose reuses the (dead) sK/sVt space behind one barrier.
// No-max softmax (scores bounded) is exact; math bit-identical to v5.
// ---------------------------------------------------------------------------
__global__ __launch_bounds__(256, 4) void flash_kernel(
    const bf16* __restrict__ qkv, const float* __restrict__ relf,
    bf16* __restrict__ attn) {
  constexpr int S = 2048, R3 = 3072;
  // union'd LDS: sK = 2 x 4096 bf16 (16384 B), sVt = 2 x 4608 bf16 (18432 B)
  __shared__ __align__(16) char smem[34816];
  bf16* const sK = (bf16*)smem;             // [buf][dchunk][key][32]
  bf16* const sVt = (bf16*)(smem + 16384);  // [buf][d][key] stride 72

  const int tid = threadIdx.x, w = tid >> 6, lane = tid & 63;
  const int n16 = lane & 15, quad = lane >> 4;
  const int qt = blockIdx.x & 15;    // 16 q-tiles of 128
  const int bh = blockIdx.x >> 4;
  const int h = bh & 15, b = bh >> 4;
  const int qb = qt * 128 + w * 32;  // this wave's first q row (within S)
  const size_t rowbase = (size_t)b * S;
  const float SC = 0.125f * 1.44269504f;  // (1/sqrt(D)) * log2(e)
  const size_t TADV = (size_t)64 * R3;    // advance one key-tile

  // Q B-frags [mi][dchunk]: lane holds B[n=n16][k=quad*8+j]
  short8 qf[2][2];
#pragma unroll
  for (int mi = 0; mi < 2; mi++) {
    const bf16* qp = qkv + (rowbase + qb + mi * 16 + n16) * R3 + h * 64;
#pragma unroll
    for (int c = 0; c < 2; c++) qf[mi][c] = *(const short8*)(qp + c * 32 + quad * 8);
  }

  f32x4 ot[4][2];  // O^T accum: [d-tile nc][q-tile mi]; row=d, col=q
#pragma unroll
  for (int nc = 0; nc < 4; nc++)
#pragma unroll
    for (int mi = 0; mi < 2; mi++) ot[nc][mi] = (f32x4){0.f, 0.f, 0.f, 0.f};
  float l_lane[2] = {0.f, 0.f};

  // ---- per-thread K-DMA source pointers (tile 0), wave-uniform LDS offsets
  const bf16* kg[2];
#pragma unroll
  for (int i = 0; i < 2; i++) {
    const int f = (i * 256 + tid) * 8;
    const int c = f >> 11, key = (f >> 5) & 63, dcol = f & 31;
    kg[i] = qkv + (rowbase + key) * R3 + 1024 + h * 64 + c * 32 + dcol;
  }
  const int kldsoff = w * 64 * 8;  // + i*256*8 within buffer

  // ---- V staging mapping: thread -> (key pair, d octet)
  const int kp = lane & 31;                  // keys 2kp, 2kp+1
  const int vd0 = w * 16 + (lane >> 5) * 8;  // 8 d values
  const bf16* vp = qkv + (rowbase + 2 * kp) * R3 + 2048 + h * 64 + vd0;

  // ---- prologue: DMA K(0) -> sK buf0; V(0) -> sVt buf0; regs V(1), rel(0)
#pragma unroll
  for (int i = 0; i < 2; i++)
    gl2lds16(kg[i], sK + kldsoff + i * 2048);
#pragma unroll
  for (int i = 0; i < 2; i++) kg[i] += TADV;  // -> tile 1

  short8 v0 = *(const short8*)vp;
  short8 v1 = *(const short8*)(vp + R3);
#pragma unroll
  for (int i = 0; i < 8; i++) {
    const unsigned int u = ((unsigned int)(unsigned short)v1[i] << 16) |
                           (unsigned int)(unsigned short)v0[i];
    *(unsigned int*)(&sVt[(vd0 + i) * 72 + 2 * kp]) = u;
  }
  vp += TADV;
  v0 = *(const short8*)vp;          // V(1) into regs
  v1 = *(const short8*)(vp + R3);
  vp += TADV;                       // -> tile 2

  float4 rv[8];
  const float4* rp = (const float4*)relf + (size_t)(qt * 32) * 2048 + w * 512 + lane;
#pragma unroll
  for (int j = 0; j < 8; j++) rv[j] = rp[j * 64];
  rp += 2048;

  for (int kt = 0; kt < 32; kt++) {
    const int cur = kt & 1, nxt = cur ^ 1;
    __syncthreads();  // drains DMA(kt) + V^T(kt) visible + prev readers done

    if (kt < 31) {
      // issue DMA K(kt+1) into other buffer; stage V^T(kt+1) from regs
#pragma unroll
      for (int i = 0; i < 2; i++) {
        gl2lds16(kg[i], sK + nxt * 4096 + kldsoff + i * 2048);
        kg[i] += TADV;
      }
#pragma unroll
      for (int i = 0; i < 8; i++) {
        const unsigned int u = ((unsigned int)(unsigned short)v1[i] << 16) |
                               (unsigned int)(unsigned short)v0[i];
        *(unsigned int*)(&sVt[nxt * 4608 + (vd0 + i) * 72 + 2 * kp]) = u;
      }
    }

#pragma unroll
    for (int kc = 0; kc < 2; kc++) {
      // ---- S^T chunk = K·Q^T for kt4 in {2kc, 2kc+1}: row=key, col=q
      f32x4 st[2][2];  // [t2][mi]
#pragma unroll
      for (int t2 = 0; t2 < 2; t2++) {
        const int kt4 = 2 * kc + t2;
        short8 kf[2];
#pragma unroll
        for (int c = 0; c < 2; c++)
          kf[c] = *(const short8*)(sK + cur * 4096 +
                                   (c * 64 + kt4 * 16 + n16) * 32 + quad * 8);
#pragma unroll
        for (int mi = 0; mi < 2; mi++) {
          f32x4 z = (f32x4){0.f, 0.f, 0.f, 0.f};
          z = MFMA16(kf[0], qf[mi][0], z);
          z = MFMA16(kf[1], qf[mi][1], z);
          st[t2][mi] = z;
        }
      }
      // ---- prefetch V(kt+2) regs once per iter (hides under exp/PV)
      if (kc == 0 && kt < 30) {
        v0 = *(const short8*)vp;
        v1 = *(const short8*)(vp + R3);
        vp += TADV;
      }
      // ---- p = 2^(s*SC + rel'), pack to bf16 dwords, permlane into PV B-frag
      short8 pb[2];  // [mi]
#pragma unroll
      for (int mi = 0; mi < 2; mi++) {
        float acc = 0.f;
        unsigned d[2][2];  // [t2][h]; dword = keys (2kc+t2)*16+quad*4+2h,+2h+1
#pragma unroll
        for (int t2 = 0; t2 < 2; t2++) {
          const float4 rr = rv[mi * 4 + 2 * kc + t2];
          float p0 = __builtin_amdgcn_exp2f(fmaf(st[t2][mi][0], SC, rr.x));
          float p1 = __builtin_amdgcn_exp2f(fmaf(st[t2][mi][1], SC, rr.y));
          float p2 = __builtin_amdgcn_exp2f(fmaf(st[t2][mi][2], SC, rr.z));
          float p3 = __builtin_amdgcn_exp2f(fmaf(st[t2][mi][3], SC, rr.w));
          acc += (p0 + p1) + (p2 + p3);
          d[t2][0] = pkbf(p0, p1);
          d[t2][1] = pkbf(p2, p3);
        }
        l_lane[mi] += acc;
        // swap1: reg (kt4&1) -> lane bit5 ; swap2: bit5 -> bit4, bit4 -> reg
        const uint2v e0 = plswap32(d[0][0], d[1][0]);  // h=0: [0]=q1:0 [1]=q1:1
        const uint2v e1 = plswap32(d[0][1], d[1][1]);  // h=1
        const uint2v f0 = plswap16(e0[0], e0[1]);      // [0]=t0, [1]=t2
        const uint2v f1 = plswap16(e1[0], e1[1]);      // [0]=t1, [1]=t3
        union { short8 s; unsigned u[4]; } P;
        P.u[0] = f0[0]; P.u[1] = f1[0]; P.u[2] = f0[1]; P.u[3] = f1[1];
        pb[mi] = P.s;  // bf16 j=0..7 = key kc*32 + quad*8 + j, col q=n16
      }
      // ---- prefetch rel(kt+1) once per iter (rv fully dead after kc=1 exp)
      if (kc == 1 && kt < 31) {
#pragma unroll
        for (int j = 0; j < 8; j++) rv[j] = rp[j * 64];
        rp += 2048;
      }
      // ---- PV chunk: O^T += V^T · P^T  (B-frag straight from registers)
      short8 va[4];
#pragma unroll
      for (int nc = 0; nc < 4; nc++)
        va[nc] = *(const short8*)(&sVt[cur * 4608 + (nc * 16 + n16) * 72 +
                                       kc * 32 + quad * 8]);
#pragma unroll
      for (int nc = 0; nc < 4; nc++)
#pragma unroll
        for (int mi = 0; mi < 2; mi++)
          ot[nc][mi] = MFMA16(va[nc], pb[mi], ot[nc][mi]);
    }
  }

  // ---- epilogue: l reduce over quads (lanes n16 / +16 / +32 / +48)
  float inv[2];
#pragma unroll
  for (int mi = 0; mi < 2; mi++) {
    float l = l_lane[mi];
    l += __shfl_xor(l, 16);
    l += __shfl_xor(l, 32);
    inv[mi] = 1.0f / l;
  }
  // sK/sVt are dead; reuse LDS as per-wave transpose scratch (needs barrier:
  // a lagging wave may still be reading sK/sVt of the final tile)
  __syncthreads();
  bf16* const sEp = (bf16*)smem + w * (32 * 72);
  // transpose O^T -> [q][d] via wave-private LDS (packed b64 writes)
#pragma unroll
  for (int mi = 0; mi < 2; mi++)
#pragma unroll
    for (int nc = 0; nc < 4; nc++) {
      uint2 pk;
      pk.x = pkbf(ot[nc][mi][0] * inv[mi], ot[nc][mi][1] * inv[mi]);
      pk.y = pkbf(ot[nc][mi][2] * inv[mi], ot[nc][mi][3] * inv[mi]);
      *(uint2*)(&sEp[(mi * 16 + n16) * 72 + nc * 16 + quad * 4]) = pk;
    }
  // coalesced store: 32 rows x 64 d, 16B per lane
#pragma unroll
  for (int t = 0; t < 4; t++) {
    const int row = t * 8 + (lane >> 3);
    const int dcol = (lane & 7) * 8;
    const short8 vrow = *(const short8*)(&sEp[row * 72 + dcol]);
    *(short8*)(attn + (rowbase + qb + row) * 1024 + h * 64 + dcol) = vrow;
  }
}

// ---------------------------------------------------------------------------
// prep: fused weight cast + bias concat + x build (block ranges)
// ---------------------------------------------------------------------------
__global__ void prep_main(const float* __restrict__ fm, const float* __restrict__ scene,
                          const float* __restrict__ Wq, const float* __restrict__ Wk,
                          const float* __restrict__ Wv, const float* __restrict__ Wo,
                          const float* __restrict__ bq, const float* __restrict__ bk,
                          const float* __restrict__ bv, bf16* __restrict__ wW,
                          bf16* __restrict__ wWo, float* __restrict__ bC,
                          bf16* __restrict__ x) {
  const int blk = blockIdx.x;
  if (blk < 4096) {
    const int sel = blk >> 10;  // 0..3
    const int i = (((blk & 1023) * 256) + threadIdx.x) * 4;
    const float* src = (sel == 0) ? Wq : (sel == 1) ? Wk : (sel == 2) ? Wv : Wo;
    bf16* dst = (sel < 3) ? (wW + ((size_t)sel << 20) + i) : (wWo + i);
    const float4 v = *(const float4*)(src + i);
    dst[0] = __float2bfloat16(v.x);
    dst[1] = __float2bfloat16(v.y);
    dst[2] = __float2bfloat16(v.z);
    dst[3] = __float2bfloat16(v.w);
    if (blk == 0) {
      for (int z = threadIdx.x; z < 3072; z += 256)
        bC[z] = (z < 1024) ? bq[z] : (z < 2048) ? bk[z - 1024] : bv[z - 2048];
    }
  } else {
    const int bx = blk - 4096;
    const size_t i = ((size_t)bx * 256 + threadIdx.x) * 4;
    const int r = (int)(i >> 10), c = (int)(i & 1023);
    const int b = r >> 11, s = r & 2047;
    const float* src = (s < 1024)
                           ? (scene + ((size_t)b << 10) + c)
                           : (fm + (((size_t)b * 1024 + (s - 1024)) << 10) + c);
    const float4 v = *(const float4*)src;
    bf16* d = x + i;
    d[0] = __float2bfloat16(v.x);
    d[1] = __float2bfloat16(v.y);
    d[2] = __float2bfloat16(v.z);
    d[3] = __float2bfloat16(v.w);
  }
}

// rel -> S^T fragment-ordered relf (x log2e). One thread per output float4;
// components are 4 consecutive keys.
__global__ void prep_rel(const float* __restrict__ rel, float* __restrict__ relf) {
  const int idx = blockIdx.x * 256 + threadIdx.x;  // 0 .. 2^20-1
  const int lane = idx & 63;
  const int j = (idx >> 6) & 7;     // mi*4 + kt4
  const int w = (idx >> 9) & 3;
  const int kt = (idx >> 11) & 31;
  const int qt = idx >> 16;
  const int n16 = lane & 15, quad = lane >> 4;
  const int mi = j >> 2, kt4 = j & 3;
  const int qrow = qt * 128 + w * 32 + mi * 16 + n16;
  const int key = kt * 64 + kt4 * 16 + quad * 4;
  const float L2E = 1.44269504f;
  float4 v = *(const float4*)(rel + (size_t)qrow * 2048 + key);
  v.x *= L2E; v.y *= L2E; v.z *= L2E; v.w *= L2E;
  ((float4*)relf)[idx] = v;
}

// ---------------------------------------------------------------------------
extern "C" void kernel_launch(void* const* d_in, const int* in_sizes, int n_in,
                              void* d_out, int out_size, void* d_ws,
                              size_t ws_size, hipStream_t stream) {
  const float* fm    = (const float*)d_in[0];
  const float* scene = (const float*)d_in[1];
  const float* rel   = (const float*)d_in[2];
  const float* Wq    = (const float*)d_in[3];
  const float* bq    = (const float*)d_in[4];
  const float* Wk    = (const float*)d_in[5];
  const float* bk    = (const float*)d_in[6];
  const float* Wv    = (const float*)d_in[7];
  const float* bv    = (const float*)d_in[8];
  const float* Wo    = (const float*)d_in[9];
  const float* bo    = (const float*)d_in[10];
  float* out = (float*)d_out;

  char* ws = (char*)d_ws;
  bf16* x    = (bf16*)(ws);                          // 16 MB  [8192,1024]
  float* relf = (float*)(ws);                        // 16 MB  (aliases x; x dead after QKV GEMM)
  bf16* qkv  = (bf16*)(ws + (16u << 20));            // 48 MB  [8192,3072]
  bf16* attn = (bf16*)(ws + (64u << 20));            // 16 MB  [8192,1024]
  bf16* wW   = (bf16*)(ws + (80u << 20));            // 6 MB   [3072,1024] Wq|Wk|Wv rows
  bf16* wWo  = (bf16*)(ws + (86u << 20));            // 2 MB   [1024,1024]
  float* bC  = (float*)(ws + (88u << 20));           // 12 KB  bq|bk|bv

  prep_main<<<12288, 256, 0, stream>>>(fm, scene, Wq, Wk, Wv, Wo, bq, bk, bv,
                                       wW, wWo, bC, x);

  // QKV fused: [8192,1024] @ [3072,1024]^T + bC -> [8192,3072] bf16
  gemm_bt<1><<<dim3(24, 64), 256, 0, stream>>>(x, wW, bC, qkv, nullptr,
                                               8192, 3072, 1024);
  // x is dead now; build fragment-ordered rel into the same region
  prep_rel<<<4096, 256, 0, stream>>>(rel, relf);
  // attention: B*H*(S/128) = 4*16*16 = 1024 blocks
  flash_kernel<<<1024, 256, 0, stream>>>(qkv, relf, attn);
  // output projection: [8192,1024] @ [1024,1024]^T + bo -> f32 out
  gemm_bt<0><<<dim3(8, 64), 256, 0, stream>>>(attn, wWo, bo, nullptr, out,
                                              8192, 1024, 1024);
}

// Round 3
// 342.248 us; speedup vs baseline: 1.1263x; 1.1263x over previous
//
#include <hip/hip_runtime.h>
#include <hip/hip_bf16.h>
#include <cstdint>

// Problem constants: B=4, N=1024, F=1024, H=16, D=64, S=2N=2048.
typedef __hip_bfloat16 bf16;
typedef __attribute__((ext_vector_type(8))) short short8;   // 8 x bf16 (4 VGPRs)
typedef __attribute__((ext_vector_type(4))) float f32x4;
typedef __attribute__((ext_vector_type(2))) unsigned int uint2v;

#define MFMA16(a, b, c) __builtin_amdgcn_mfma_f32_16x16x32_bf16((a), (b), (c), 0, 0, 0)

__device__ __forceinline__ void gl2lds16(const void* g, void* l) {
  // async global->LDS, 16B/lane; LDS dest = wave-uniform base + lane*16
  __builtin_amdgcn_global_load_lds(
      (const __attribute__((address_space(1))) unsigned int*)g,
      (__attribute__((address_space(3))) unsigned int*)l,
      16, 0, 0);
}

// pack two f32 -> bf16x2, round-half-up (3 VALU ops: add, add, v_perm)
__device__ __forceinline__ unsigned int pkbf(float a, float b) {
  const unsigned int ua = __builtin_bit_cast(unsigned int, a) + 0x8000u;
  const unsigned int ub = __builtin_bit_cast(unsigned int, b) + 0x8000u;
  return __builtin_amdgcn_perm(ub, ua, 0x07060302u);  // {hi16(ub), hi16(ua)}
}

// Collect-swap across lane bit 5: r[0] = values from lanes bit5==0 of {a,b}
// (lane bit5 encodes source reg), r[1] = values from lanes bit5==1.
__device__ __forceinline__ uint2v plswap32(unsigned a, unsigned b) {
#if __has_builtin(__builtin_amdgcn_permlane32_swap)
  return __builtin_amdgcn_permlane32_swap(a, b, false, false);
#else
  const unsigned ax = __shfl_xor((int)a, 32), bx = __shfl_xor((int)b, 32);
  const bool hi = (threadIdx.x & 32) != 0;
  uint2v r;
  r[0] = hi ? bx : a;
  r[1] = hi ? b : ax;
  return r;
#endif
}

// Collect-swap across lane bit 4 (16-lane rows), same collect semantics.
__device__ __forceinline__ uint2v plswap16(unsigned a, unsigned b) {
#if __has_builtin(__builtin_amdgcn_permlane16_swap)
  return __builtin_amdgcn_permlane16_swap(a, b, false, false);
#else
  const unsigned ax = __shfl_xor((int)a, 16), bx = __shfl_xor((int)b, 16);
  const bool hi = (threadIdx.x & 16) != 0;
  uint2v r;
  r[0] = hi ? bx : a;
  r[1] = hi ? b : ax;
  return r;
#endif
}

// ---------------------------------------------------------------------------
// C[M,N] = A[M,K] @ Bt[N,K]^T + bias   (all bf16 in, fp32 accum)
// 128x128 tile, BK=32, 256 threads (4 waves in 2x2), 16x16x32 bf16 MFMA.
// ---------------------------------------------------------------------------
template <int WRITE_BF16>
__global__ __launch_bounds__(256) void gemm_bt(
    const bf16* __restrict__ A, const bf16* __restrict__ Bt,
    const float* __restrict__ bias, bf16* __restrict__ outb,
    float* __restrict__ outf, int M, int N, int K) {
  __shared__ bf16 sA[128 * 32];
  __shared__ bf16 sB[128 * 32];
  const int tid = threadIdx.x, w = tid >> 6, lane = tid & 63;
  const int n16 = lane & 15, quad = lane >> 4;
  const int mBase = blockIdx.y * 128, nBase = blockIdx.x * 128;
  const int wr = w >> 1, wc = w & 1;  // wave covers rows wr*64.., cols wc*64..

  f32x4 acc[4][4];
#pragma unroll
  for (int mi = 0; mi < 4; mi++)
#pragma unroll
    for (int ni = 0; ni < 4; ni++) acc[mi][ni] = (f32x4){0.f, 0.f, 0.f, 0.f};

  for (int k0 = 0; k0 < K; k0 += 32) {
    __syncthreads();  // previous iteration's frag reads must finish
#pragma unroll
    for (int i = 0; i < 2; i++) {
      const int f = (i * 256 + w * 64 + lane) * 8;  // element in 128x32 tile
      const int row = f >> 5, col = f & 31;
      bf16* ldsbase_a = sA + (i * 256 + w * 64) * 8;  // wave-uniform
      bf16* ldsbase_b = sB + (i * 256 + w * 64) * 8;
      gl2lds16(A + (size_t)(mBase + row) * K + k0 + col, ldsbase_a);
      gl2lds16(Bt + (size_t)(nBase + row) * K + k0 + col, ldsbase_b);
    }
    __syncthreads();  // drains vmcnt (global_load_lds) + makes LDS visible

    short8 af[4], bfg[4];
#pragma unroll
    for (int t = 0; t < 4; t++) {
      af[t] = *(const short8*)(sA + (wr * 64 + t * 16 + n16) * 32 + quad * 8);
      bfg[t] = *(const short8*)(sB + (wc * 64 + t * 16 + n16) * 32 + quad * 8);
    }
#pragma unroll
    for (int mi = 0; mi < 4; mi++)
#pragma unroll
      for (int ni = 0; ni < 4; ni++)
        acc[mi][ni] = MFMA16(af[mi], bfg[ni], acc[mi][ni]);
  }

  // Epilogue. C/D layout: col = lane&15, row = quad*4 + reg  [verified m89/m91]
#pragma unroll
  for (int mi = 0; mi < 4; mi++)
#pragma unroll
    for (int ni = 0; ni < 4; ni++)
#pragma unroll
      for (int r = 0; r < 4; r++) {
        const int row = mBase + wr * 64 + mi * 16 + quad * 4 + r;
        const int col = nBase + wc * 64 + ni * 16 + n16;
        const float v = acc[mi][ni][r] + bias[col];
        if (WRITE_BF16)
          outb[(size_t)row * N + col] = __float2bfloat16(v);
        else
          outf[(size_t)row * N + col] = v;
      }
}

// ---------------------------------------------------------------------------
// Flash attention v7 = v6 structure with plain __launch_bounds__(256).
// v6 lesson: forcing min-waves=4 made the allocator squeeze arch-VGPRs to 64
// (unified VGPR/AGPR split) -> massive scratch spills (FETCH +81MB, WRITE
// +44MB, dur 147->179us). The natural allocation (v5: 112 regs) is already
// within the 128-VGPR tier needed for 4 waves/SIMD; the LDS cut to 34816 B
// is what unlocks 4 blocks/CU. So: LDS lever kept, register lever freed.
//   - sPT eliminated; P^T re-laid-out S^T-frag -> PV-B-frag in registers via
//     permlane32_swap + permlane16_swap ({bit5, bit4, reg} 3-cycle).
//   - K-loop per-kc (two 32-key chunks) halves st/pb liveness.
//   - Epilogue transpose reuses dead sK/sVt space behind one barrier.
// No-max softmax (scores bounded) is exact; math bit-identical to v5.
// ---------------------------------------------------------------------------
__global__ __launch_bounds__(256) void flash_kernel(
    const bf16* __restrict__ qkv, const float* __restrict__ relf,
    bf16* __restrict__ attn) {
  constexpr int S = 2048, R3 = 3072;
  // union'd LDS: sK = 2 x 4096 bf16 (16384 B), sVt = 2 x 4608 bf16 (18432 B)
  __shared__ __align__(16) char smem[34816];
  bf16* const sK = (bf16*)smem;             // [buf][dchunk][key][32]
  bf16* const sVt = (bf16*)(smem + 16384);  // [buf][d][key] stride 72

  const int tid = threadIdx.x, w = tid >> 6, lane = tid & 63;
  const int n16 = lane & 15, quad = lane >> 4;
  const int qt = blockIdx.x & 15;    // 16 q-tiles of 128
  const int bh = blockIdx.x >> 4;
  const int h = bh & 15, b = bh >> 4;
  const int qb = qt * 128 + w * 32;  // this wave's first q row (within S)
  const size_t rowbase = (size_t)b * S;
  const float SC = 0.125f * 1.44269504f;  // (1/sqrt(D)) * log2(e)
  const size_t TADV = (size_t)64 * R3;    // advance one key-tile

  // Q B-frags [mi][dchunk]: lane holds B[n=n16][k=quad*8+j]
  short8 qf[2][2];
#pragma unroll
  for (int mi = 0; mi < 2; mi++) {
    const bf16* qp = qkv + (rowbase + qb + mi * 16 + n16) * R3 + h * 64;
#pragma unroll
    for (int c = 0; c < 2; c++) qf[mi][c] = *(const short8*)(qp + c * 32 + quad * 8);
  }

  f32x4 ot[4][2];  // O^T accum: [d-tile nc][q-tile mi]; row=d, col=q
#pragma unroll
  for (int nc = 0; nc < 4; nc++)
#pragma unroll
    for (int mi = 0; mi < 2; mi++) ot[nc][mi] = (f32x4){0.f, 0.f, 0.f, 0.f};
  float l_lane[2] = {0.f, 0.f};

  // ---- per-thread K-DMA source pointers (tile 0), wave-uniform LDS offsets
  const bf16* kg[2];
#pragma unroll
  for (int i = 0; i < 2; i++) {
    const int f = (i * 256 + tid) * 8;
    const int c = f >> 11, key = (f >> 5) & 63, dcol = f & 31;
    kg[i] = qkv + (rowbase + key) * R3 + 1024 + h * 64 + c * 32 + dcol;
  }
  const int kldsoff = w * 64 * 8;  // + i*256*8 within buffer

  // ---- V staging mapping: thread -> (key pair, d octet)
  const int kp = lane & 31;                  // keys 2kp, 2kp+1
  const int vd0 = w * 16 + (lane >> 5) * 8;  // 8 d values
  const bf16* vp = qkv + (rowbase + 2 * kp) * R3 + 2048 + h * 64 + vd0;

  // ---- prologue: DMA K(0) -> sK buf0; V(0) -> sVt buf0; regs V(1), rel(0)
#pragma unroll
  for (int i = 0; i < 2; i++)
    gl2lds16(kg[i], sK + kldsoff + i * 2048);
#pragma unroll
  for (int i = 0; i < 2; i++) kg[i] += TADV;  // -> tile 1

  short8 v0 = *(const short8*)vp;
  short8 v1 = *(const short8*)(vp + R3);
#pragma unroll
  for (int i = 0; i < 8; i++) {
    const unsigned int u = ((unsigned int)(unsigned short)v1[i] << 16) |
                           (unsigned int)(unsigned short)v0[i];
    *(unsigned int*)(&sVt[(vd0 + i) * 72 + 2 * kp]) = u;
  }
  vp += TADV;
  v0 = *(const short8*)vp;          // V(1) into regs
  v1 = *(const short8*)(vp + R3);
  vp += TADV;                       // -> tile 2

  float4 rv[8];
  const float4* rp = (const float4*)relf + (size_t)(qt * 32) * 2048 + w * 512 + lane;
#pragma unroll
  for (int j = 0; j < 8; j++) rv[j] = rp[j * 64];
  rp += 2048;

  for (int kt = 0; kt < 32; kt++) {
    const int cur = kt & 1, nxt = cur ^ 1;
    __syncthreads();  // drains DMA(kt) + V^T(kt) visible + prev readers done

    if (kt < 31) {
      // issue DMA K(kt+1) into other buffer; stage V^T(kt+1) from regs
#pragma unroll
      for (int i = 0; i < 2; i++) {
        gl2lds16(kg[i], sK + nxt * 4096 + kldsoff + i * 2048);
        kg[i] += TADV;
      }
#pragma unroll
      for (int i = 0; i < 8; i++) {
        const unsigned int u = ((unsigned int)(unsigned short)v1[i] << 16) |
                               (unsigned int)(unsigned short)v0[i];
        *(unsigned int*)(&sVt[nxt * 4608 + (vd0 + i) * 72 + 2 * kp]) = u;
      }
    }

#pragma unroll
    for (int kc = 0; kc < 2; kc++) {
      // ---- S^T chunk = K·Q^T for kt4 in {2kc, 2kc+1}: row=key, col=q
      f32x4 st[2][2];  // [t2][mi]
#pragma unroll
      for (int t2 = 0; t2 < 2; t2++) {
        const int kt4 = 2 * kc + t2;
        short8 kf[2];
#pragma unroll
        for (int c = 0; c < 2; c++)
          kf[c] = *(const short8*)(sK + cur * 4096 +
                                   (c * 64 + kt4 * 16 + n16) * 32 + quad * 8);
#pragma unroll
        for (int mi = 0; mi < 2; mi++) {
          f32x4 z = (f32x4){0.f, 0.f, 0.f, 0.f};
          z = MFMA16(kf[0], qf[mi][0], z);
          z = MFMA16(kf[1], qf[mi][1], z);
          st[t2][mi] = z;
        }
      }
      // ---- prefetch V(kt+2) regs once per iter (hides under exp/PV)
      if (kc == 0 && kt < 30) {
        v0 = *(const short8*)vp;
        v1 = *(const short8*)(vp + R3);
        vp += TADV;
      }
      // ---- p = 2^(s*SC + rel'), pack to bf16 dwords, permlane into PV B-frag
      short8 pb[2];  // [mi]
#pragma unroll
      for (int mi = 0; mi < 2; mi++) {
        float acc = 0.f;
        unsigned d[2][2];  // [t2][h]; dword = keys (2kc+t2)*16+quad*4+2h,+2h+1
#pragma unroll
        for (int t2 = 0; t2 < 2; t2++) {
          const float4 rr = rv[mi * 4 + 2 * kc + t2];
          float p0 = __builtin_amdgcn_exp2f(fmaf(st[t2][mi][0], SC, rr.x));
          float p1 = __builtin_amdgcn_exp2f(fmaf(st[t2][mi][1], SC, rr.y));
          float p2 = __builtin_amdgcn_exp2f(fmaf(st[t2][mi][2], SC, rr.z));
          float p3 = __builtin_amdgcn_exp2f(fmaf(st[t2][mi][3], SC, rr.w));
          acc += (p0 + p1) + (p2 + p3);
          d[t2][0] = pkbf(p0, p1);
          d[t2][1] = pkbf(p2, p3);
        }
        l_lane[mi] += acc;
        // swap1: reg (kt4&1) -> lane bit5 ; swap2: bit5 -> bit4, bit4 -> reg
        const uint2v e0 = plswap32(d[0][0], d[1][0]);  // h=0: [0]=q1:0 [1]=q1:1
        const uint2v e1 = plswap32(d[0][1], d[1][1]);  // h=1
        const uint2v f0 = plswap16(e0[0], e0[1]);      // [0]=t0, [1]=t2
        const uint2v f1 = plswap16(e1[0], e1[1]);      // [0]=t1, [1]=t3
        union { short8 s; unsigned u[4]; } P;
        P.u[0] = f0[0]; P.u[1] = f1[0]; P.u[2] = f0[1]; P.u[3] = f1[1];
        pb[mi] = P.s;  // bf16 j=0..7 = key kc*32 + quad*8 + j, col q=n16
      }
      // ---- prefetch rel(kt+1) once per iter (rv fully dead after kc=1 exp)
      if (kc == 1 && kt < 31) {
#pragma unroll
        for (int j = 0; j < 8; j++) rv[j] = rp[j * 64];
        rp += 2048;
      }
      // ---- PV chunk: O^T += V^T · P^T  (B-frag straight from registers)
      short8 va[4];
#pragma unroll
      for (int nc = 0; nc < 4; nc++)
        va[nc] = *(const short8*)(&sVt[cur * 4608 + (nc * 16 + n16) * 72 +
                                       kc * 32 + quad * 8]);
#pragma unroll
      for (int nc = 0; nc < 4; nc++)
#pragma unroll
        for (int mi = 0; mi < 2; mi++)
          ot[nc][mi] = MFMA16(va[nc], pb[mi], ot[nc][mi]);
    }
  }

  // ---- epilogue: l reduce over quads (lanes n16 / +16 / +32 / +48)
  float inv[2];
#pragma unroll
  for (int mi = 0; mi < 2; mi++) {
    float l = l_lane[mi];
    l += __shfl_xor(l, 16);
    l += __shfl_xor(l, 32);
    inv[mi] = 1.0f / l;
  }
  // sK/sVt are dead; reuse LDS as per-wave transpose scratch (needs barrier:
  // a lagging wave may still be reading sK/sVt of the final tile)
  __syncthreads();
  bf16* const sEp = (bf16*)smem + w * (32 * 72);
  // transpose O^T -> [q][d] via wave-private LDS (packed b64 writes)
#pragma unroll
  for (int mi = 0; mi < 2; mi++)
#pragma unroll
    for (int nc = 0; nc < 4; nc++) {
      uint2 pk;
      pk.x = pkbf(ot[nc][mi][0] * inv[mi], ot[nc][mi][1] * inv[mi]);
      pk.y = pkbf(ot[nc][mi][2] * inv[mi], ot[nc][mi][3] * inv[mi]);
      *(uint2*)(&sEp[(mi * 16 + n16) * 72 + nc * 16 + quad * 4]) = pk;
    }
  // coalesced store: 32 rows x 64 d, 16B per lane
#pragma unroll
  for (int t = 0; t < 4; t++) {
    const int row = t * 8 + (lane >> 3);
    const int dcol = (lane & 7) * 8;
    const short8 vrow = *(const short8*)(&sEp[row * 72 + dcol]);
    *(short8*)(attn + (rowbase + qb + row) * 1024 + h * 64 + dcol) = vrow;
  }
}

// ---------------------------------------------------------------------------
// prep: fused weight cast + bias concat + x build (block ranges)
// ---------------------------------------------------------------------------
__global__ void prep_main(const float* __restrict__ fm, const float* __restrict__ scene,
                          const float* __restrict__ Wq, const float* __restrict__ Wk,
                          const float* __restrict__ Wv, const float* __restrict__ Wo,
                          const float* __restrict__ bq, const float* __restrict__ bk,
                          const float* __restrict__ bv, bf16* __restrict__ wW,
                          bf16* __restrict__ wWo, float* __restrict__ bC,
                          bf16* __restrict__ x) {
  const int blk = blockIdx.x;
  if (blk < 4096) {
    const int sel = blk >> 10;  // 0..3
    const int i = (((blk & 1023) * 256) + threadIdx.x) * 4;
    const float* src = (sel == 0) ? Wq : (sel == 1) ? Wk : (sel == 2) ? Wv : Wo;
    bf16* dst = (sel < 3) ? (wW + ((size_t)sel << 20) + i) : (wWo + i);
    const float4 v = *(const float4*)(src + i);
    dst[0] = __float2bfloat16(v.x);
    dst[1] = __float2bfloat16(v.y);
    dst[2] = __float2bfloat16(v.z);
    dst[3] = __float2bfloat16(v.w);
    if (blk == 0) {
      for (int z = threadIdx.x; z < 3072; z += 256)
        bC[z] = (z < 1024) ? bq[z] : (z < 2048) ? bk[z - 1024] : bv[z - 2048];
    }
  } else {
    const int bx = blk - 4096;
    const size_t i = ((size_t)bx * 256 + threadIdx.x) * 4;
    const int r = (int)(i >> 10), c = (int)(i & 1023);
    const int b = r >> 11, s = r & 2047;
    const float* src = (s < 1024)
                           ? (scene + ((size_t)b << 10) + c)
                           : (fm + (((size_t)b * 1024 + (s - 1024)) << 10) + c);
    const float4 v = *(const float4*)src;
    bf16* d = x + i;
    d[0] = __float2bfloat16(v.x);
    d[1] = __float2bfloat16(v.y);
    d[2] = __float2bfloat16(v.z);
    d[3] = __float2bfloat16(v.w);
  }
}

// rel -> S^T fragment-ordered relf (x log2e). One thread per output float4;
// components are 4 consecutive keys.
__global__ void prep_rel(const float* __restrict__ rel, float* __restrict__ relf) {
  const int idx = blockIdx.x * 256 + threadIdx.x;  // 0 .. 2^20-1
  const int lane = idx & 63;
  const int j = (idx >> 6) & 7;     // mi*4 + kt4
  const int w = (idx >> 9) & 3;
  const int kt = (idx >> 11) & 31;
  const int qt = idx >> 16;
  const int n16 = lane & 15, quad = lane >> 4;
  const int mi = j >> 2, kt4 = j & 3;
  const int qrow = qt * 128 + w * 32 + mi * 16 + n16;
  const int key = kt * 64 + kt4 * 16 + quad * 4;
  const float L2E = 1.44269504f;
  float4 v = *(const float4*)(rel + (size_t)qrow * 2048 + key);
  v.x *= L2E; v.y *= L2E; v.z *= L2E; v.w *= L2E;
  ((float4*)relf)[idx] = v;
}

// ---------------------------------------------------------------------------
extern "C" void kernel_launch(void* const* d_in, const int* in_sizes, int n_in,
                              void* d_out, int out_size, void* d_ws,
                              size_t ws_size, hipStream_t stream) {
  const float* fm    = (const float*)d_in[0];
  const float* scene = (const float*)d_in[1];
  const float* rel   = (const float*)d_in[2];
  const float* Wq    = (const float*)d_in[3];
  const float* bq    = (const float*)d_in[4];
  const float* Wk    = (const float*)d_in[5];
  const float* bk    = (const float*)d_in[6];
  const float* Wv    = (const float*)d_in[7];
  const float* bv    = (const float*)d_in[8];
  const float* Wo    = (const float*)d_in[9];
  const float* bo    = (const float*)d_in[10];
  float* out = (float*)d_out;

  char* ws = (char*)d_ws;
  bf16* x    = (bf16*)(ws);                          // 16 MB  [8192,1024]
  float* relf = (float*)(ws);                        // 16 MB  (aliases x; x dead after QKV GEMM)
  bf16* qkv  = (bf16*)(ws + (16u << 20));            // 48 MB  [8192,3072]
  bf16* attn = (bf16*)(ws + (64u << 20));            // 16 MB  [8192,1024]
  bf16* wW   = (bf16*)(ws + (80u << 20));            // 6 MB   [3072,1024] Wq|Wk|Wv rows
  bf16* wWo  = (bf16*)(ws + (86u << 20));            // 2 MB   [1024,1024]
  float* bC  = (float*)(ws + (88u << 20));           // 12 KB  bq|bk|bv

  prep_main<<<12288, 256, 0, stream>>>(fm, scene, Wq, Wk, Wv, Wo, bq, bk, bv,
                                       wW, wWo, bC, x);

  // QKV fused: [8192,1024] @ [3072,1024]^T + bC -> [8192,3072] bf16
  gemm_bt<1><<<dim3(24, 64), 256, 0, stream>>>(x, wW, bC, qkv, nullptr,
                                               8192, 3072, 1024);
  // x is dead now; build fragment-ordered rel into the same region
  prep_rel<<<4096, 256, 0, stream>>>(rel, relf);
  // attention: B*H*(S/128) = 4*16*16 = 1024 blocks
  flash_kernel<<<1024, 256, 0, stream>>>(qkv, relf, attn);
  // output projection: [8192,1024] @ [1024,1024]^T + bo -> f32 out
  gemm_bt<0><<<dim3(8, 64), 256, 0, stream>>>(attn, wWo, bo, nullptr, out,
                                              8192, 1024, 1024);
}

// Round 5
// 332.413 us; speedup vs baseline: 1.1596x; 1.0296x over previous
//
#include <hip/hip_runtime.h>
#include <hip/hip_bf16.h>
#include <cstdint>

// Problem constants: B=4, N=1024, F=1024, H=16, D=64, S=2N=2048.
typedef __hip_bfloat16 bf16;
typedef __attribute__((ext_vector_type(8))) short short8;   // 8 x bf16 (4 VGPRs)
typedef __attribute__((ext_vector_type(4))) float f32x4;
typedef __attribute__((ext_vector_type(2))) unsigned int uint2v;

#define MFMA16(a, b, c) __builtin_amdgcn_mfma_f32_16x16x32_bf16((a), (b), (c), 0, 0, 0)

__device__ __forceinline__ void gl2lds16(const void* g, void* l) {
  // async global->LDS, 16B/lane; LDS dest = wave-uniform base + lane*16
  __builtin_amdgcn_global_load_lds(
      (const __attribute__((address_space(1))) unsigned int*)g,
      (__attribute__((address_space(3))) unsigned int*)l,
      16, 0, 0);
}

// pack two f32 -> bf16x2 in ONE VALU op (RNE). lo16 = bf16(a), hi16 = bf16(b).
__device__ __forceinline__ unsigned int pkcvt(float a, float b) {
  unsigned int r;
  asm("v_cvt_pk_bf16_f32 %0, %1, %2" : "=v"(r) : "v"(a), "v"(b));
  return r;
}

// Collect-swap across lane bit 5: r[0] = values from lanes bit5==0 of {a,b}
// (lane bit5 encodes source reg), r[1] = values from lanes bit5==1.
__device__ __forceinline__ uint2v plswap32(unsigned a, unsigned b) {
#if __has_builtin(__builtin_amdgcn_permlane32_swap)
  return __builtin_amdgcn_permlane32_swap(a, b, false, false);
#else
  const unsigned ax = __shfl_xor((int)a, 32), bx = __shfl_xor((int)b, 32);
  const bool hi = (threadIdx.x & 32) != 0;
  uint2v r;
  r[0] = hi ? bx : a;
  r[1] = hi ? b : ax;
  return r;
#endif
}

// Collect-swap across lane bit 4 (16-lane rows), same collect semantics.
__device__ __forceinline__ uint2v plswap16(unsigned a, unsigned b) {
#if __has_builtin(__builtin_amdgcn_permlane16_swap)
  return __builtin_amdgcn_permlane16_swap(a, b, false, false);
#else
  const unsigned ax = __shfl_xor((int)a, 16), bx = __shfl_xor((int)b, 16);
  const bool hi = (threadIdx.x & 16) != 0;
  uint2v r;
  r[0] = hi ? bx : a;
  r[1] = hi ? b : ax;
  return r;
#endif
}

template <int V> struct IC { static constexpr int value = V; };

// ---------------------------------------------------------------------------
// C[M,N] = A[M,K] @ Bt[N,K]^T + bias   (all bf16 in, fp32 accum)
// 128x128 tile, BK=32, 256 threads (4 waves in 2x2), 16x16x32 bf16 MFMA.
// ---------------------------------------------------------------------------
template <int WRITE_BF16>
__global__ __launch_bounds__(256) void gemm_bt(
    const bf16* __restrict__ A, const bf16* __restrict__ Bt,
    const float* __restrict__ bias, bf16* __restrict__ outb,
    float* __restrict__ outf, int M, int N, int K) {
  __shared__ bf16 sA[128 * 32];
  __shared__ bf16 sB[128 * 32];
  const int tid = threadIdx.x, w = tid >> 6, lane = tid & 63;
  const int n16 = lane & 15, quad = lane >> 4;
  const int mBase = blockIdx.y * 128, nBase = blockIdx.x * 128;
  const int wr = w >> 1, wc = w & 1;  // wave covers rows wr*64.., cols wc*64..

  f32x4 acc[4][4];
#pragma unroll
  for (int mi = 0; mi < 4; mi++)
#pragma unroll
    for (int ni = 0; ni < 4; ni++) acc[mi][ni] = (f32x4){0.f, 0.f, 0.f, 0.f};

  for (int k0 = 0; k0 < K; k0 += 32) {
    __syncthreads();  // previous iteration's frag reads must finish
#pragma unroll
    for (int i = 0; i < 2; i++) {
      const int f = (i * 256 + w * 64 + lane) * 8;  // element in 128x32 tile
      const int row = f >> 5, col = f & 31;
      bf16* ldsbase_a = sA + (i * 256 + w * 64) * 8;  // wave-uniform
      bf16* ldsbase_b = sB + (i * 256 + w * 64) * 8;
      gl2lds16(A + (size_t)(mBase + row) * K + k0 + col, ldsbase_a);
      gl2lds16(Bt + (size_t)(nBase + row) * K + k0 + col, ldsbase_b);
    }
    __syncthreads();  // drains vmcnt (global_load_lds) + makes LDS visible

    short8 af[4], bfg[4];
#pragma unroll
    for (int t = 0; t < 4; t++) {
      af[t] = *(const short8*)(sA + (wr * 64 + t * 16 + n16) * 32 + quad * 8);
      bfg[t] = *(const short8*)(sB + (wc * 64 + t * 16 + n16) * 32 + quad * 8);
    }
#pragma unroll
    for (int mi = 0; mi < 4; mi++)
#pragma unroll
      for (int ni = 0; ni < 4; ni++)
        acc[mi][ni] = MFMA16(af[mi], bfg[ni], acc[mi][ni]);
  }

  // Epilogue. C/D layout: col = lane&15, row = quad*4 + reg  [verified m89/m91]
#pragma unroll
  for (int mi = 0; mi < 4; mi++)
#pragma unroll
    for (int ni = 0; ni < 4; ni++)
#pragma unroll
      for (int r = 0; r < 4; r++) {
        const int row = mBase + wr * 64 + mi * 16 + quad * 4 + r;
        const int col = nBase + wc * 64 + ni * 16 + n16;
        const float v = acc[mi][ni][r] + bias[col];
        if (WRITE_BF16)
          outb[(size_t)row * N + col] = __float2bfloat16(v);
        else
          outf[(size_t)row * N + col] = v;
      }
}

// ---------------------------------------------------------------------------
// Flash attention v9. v7 post-mortem: time invariant to occupancy caps ->
// per-wave bound; VALUBusy 54% implies ~1400 VALU cy/wave-iter vs ~570 needed.
// Changes (all glue-VALU / latency cuts, math identical except RNE packing):
//  - V pack via v_perm_b32 (8 ops, was ~32 extract/shl/or)
//  - pkbf (3 ops) -> v_cvt_pk_bf16_f32 (1 op) everywhere
//  - kt unrolled x2: CUR/NXT compile-time, LDS addrs = lane base + immediate
//  - sVt: stride-72 pad -> stride-64 + XOR swizzle (off ^= (d&7)<<4), both
//    sides; LDS 34816 -> 32768 (5 blocks/CU cap). Read bases precomputed.
//  - XCD-aware block swizzle: 16 q-tiles of one bh per XCD -> K/V L2-resident.
// ---------------------------------------------------------------------------
__global__ __launch_bounds__(256) void flash_kernel(
    const bf16* __restrict__ qkv, const float* __restrict__ relf,
    bf16* __restrict__ attn) {
  constexpr int S = 2048, R3 = 3072;
  // sK = 2 x 4096 bf16 (16384 B) + sVt = 2 x [64][64] bf16 swizzled (16384 B)
  __shared__ __align__(16) char smem[32768];
  bf16* const sK = (bf16*)smem;       // [buf][dchunk][key][32] linear (DMA dest)
  char* const sVtB = smem + 16384;    // [buf][d][key] 128 B rows, XOR-swizzled

  const int tid = threadIdx.x, w = tid >> 6, lane = tid & 63;
  const int n16 = lane & 15, quad = lane >> 4;
  // XCD swizzle: HW blocks i === x (mod 8) -> XCD x; give XCD x logical blocks
  // [x*128, x*128+128) = bh in [x*8, x*8+8), all 16 q-tiles of each bh together.
  const int lg = (blockIdx.x & 7) * 128 + (blockIdx.x >> 3);
  const int qt = lg & 15;            // 16 q-tiles of 128
  const int bh = lg >> 4;
  const int h = bh & 15, b = bh >> 4;
  const int qb = qt * 128 + w * 32;  // this wave's first q row (within S)
  const size_t rowbase = (size_t)b * S;
  const float SC = 0.125f * 1.44269504f;  // (1/sqrt(D)) * log2(e)
  const size_t TADV = (size_t)64 * R3;    // advance one key-tile

  // Q B-frags [mi][dchunk]: lane holds B[n=n16][k=quad*8+j]
  short8 qf[2][2];
#pragma unroll
  for (int mi = 0; mi < 2; mi++) {
    const bf16* qp = qkv + (rowbase + qb + mi * 16 + n16) * R3 + h * 64;
#pragma unroll
    for (int c = 0; c < 2; c++) qf[mi][c] = *(const short8*)(qp + c * 32 + quad * 8);
  }

  f32x4 ot[4][2];  // O^T accum: [d-tile nc][q-tile mi]; row=d, col=q
#pragma unroll
  for (int nc = 0; nc < 4; nc++)
#pragma unroll
    for (int mi = 0; mi < 2; mi++) ot[nc][mi] = (f32x4){0.f, 0.f, 0.f, 0.f};
  float l_lane[2] = {0.f, 0.f};

  // ---- per-thread K-DMA source pointers (tile 0), wave-uniform LDS offsets
  const bf16* kg0;
  const bf16* kg1;
  {
    const int f0 = tid * 8;
    const int f1 = (256 + tid) * 8;
    kg0 = qkv + (rowbase + ((f0 >> 5) & 63)) * R3 + 1024 + h * 64 +
          ((f0 >> 11) * 32) + (f0 & 31);
    kg1 = qkv + (rowbase + ((f1 >> 5) & 63)) * R3 + 1024 + h * 64 +
          ((f1 >> 11) * 32) + (f1 & 31);
  }
  const int kldsoff = w * 64 * 8;  // + i*256*8 within buffer

  // ---- V staging mapping: thread -> (key pair, d octet)
  const int kp = lane & 31;                  // keys 2kp, 2kp+1
  const int vd0 = w * 16 + (lane >> 5) * 8;  // 8 d values (multiple of 8)
  const int kp4 = kp * 4;                    // unswizzled in-row byte of key pair
  const bf16* vp = qkv + (rowbase + 2 * kp) * R3 + 2048 + h * 64 + vd0;

  // ---- sVt swizzled read bases (per-lane, once): row d = nc*16+n16;
  // in-row byte u = 64*kc + 16*quad, stored at u ^ ((d&7)<<4) = u ^ ((n16&7)<<4)
  const int vb0 = 128 * n16 + ((16 * quad) ^ ((n16 & 7) << 4));  // kc=0
  const int vb1 = vb0 ^ 64;                                      // kc=1

  short8 v0, v1;
  // stage V^T tile from regs into sVt[BUF] (v_perm pack + swizzled dword writes)
  auto vstage = [&](int bufbyte) {
    const unsigned* a1 = (const unsigned*)&v1;
    const unsigned* a0 = (const unsigned*)&v0;
#pragma unroll
    for (int j = 0; j < 4; j++) {
      // u_even = {v1[2j].lo16 : v0[2j].lo16}, u_odd from hi16 halves
      const unsigned lo = __builtin_amdgcn_perm(a1[j], a0[j], 0x05040100u);
      const unsigned hi = __builtin_amdgcn_perm(a1[j], a0[j], 0x07060302u);
      *(unsigned*)(sVtB + bufbyte + 128 * (vd0 + 2 * j) + (kp4 ^ ((2 * j) << 4))) = lo;
      *(unsigned*)(sVtB + bufbyte + 128 * (vd0 + 2 * j + 1) + (kp4 ^ ((2 * j + 1) << 4))) = hi;
    }
  };

  // ---- prologue: DMA K(0) -> sK buf0; V(0) -> sVt buf0; regs V(1), rel(0)
  gl2lds16(kg0, sK + kldsoff);
  gl2lds16(kg1, sK + kldsoff + 2048);
  kg0 += TADV;
  kg1 += TADV;

  v0 = *(const short8*)vp;
  v1 = *(const short8*)(vp + R3);
  vstage(0);
  vp += TADV;
  v0 = *(const short8*)vp;          // V(1) into regs
  v1 = *(const short8*)(vp + R3);
  vp += TADV;                       // -> tile 2

  float4 rv[8];
  const float4* rp = (const float4*)relf + (size_t)(qt * 32) * 2048 + w * 512 + lane;
#pragma unroll
  for (int j = 0; j < 8; j++) rv[j] = rp[j * 64];
  rp += 2048;

  // one kt iteration; CUR is compile-time (static LDS offsets)
  auto step = [&](auto curc, bool dodma, bool dovpf) {
    constexpr int CUR = decltype(curc)::value;
    constexpr int NXT = CUR ^ 1;
    __syncthreads();  // drains DMA(kt) + V^T(kt) visible + prev readers done

    if (dodma) {
      gl2lds16(kg0, sK + NXT * 4096 + kldsoff);
      kg0 += TADV;
      gl2lds16(kg1, sK + NXT * 4096 + kldsoff + 2048);
      kg1 += TADV;
      vstage(NXT * 8192);
    }

#pragma unroll
    for (int kc = 0; kc < 2; kc++) {
      // ---- S^T chunk = K.Q^T for kt4 in {2kc, 2kc+1}: row=key, col=q
      f32x4 st[2][2];  // [t2][mi]
#pragma unroll
      for (int t2 = 0; t2 < 2; t2++) {
        const int kt4 = 2 * kc + t2;
        short8 kf[2];
#pragma unroll
        for (int c = 0; c < 2; c++)
          kf[c] = *(const short8*)(sK + CUR * 4096 +
                                   (c * 64 + kt4 * 16 + n16) * 32 + quad * 8);
#pragma unroll
        for (int mi = 0; mi < 2; mi++) {
          f32x4 z = (f32x4){0.f, 0.f, 0.f, 0.f};
          z = MFMA16(kf[0], qf[mi][0], z);
          z = MFMA16(kf[1], qf[mi][1], z);
          st[t2][mi] = z;
        }
      }
      // ---- prefetch V(kt+2) regs once per iter (hides under exp/PV)
      if (kc == 0 && dovpf) {
        v0 = *(const short8*)vp;
        v1 = *(const short8*)(vp + R3);
        vp += TADV;
      }
      // ---- p = 2^(s*SC + rel'), cvt_pk to bf16, permlane into PV B-frag
      short8 pb[2];  // [mi]
#pragma unroll
      for (int mi = 0; mi < 2; mi++) {
        float acc = 0.f;
        unsigned d[2][2];  // [t2][h]; dword = keys (2kc+t2)*16+quad*4+2h,+2h+1
#pragma unroll
        for (int t2 = 0; t2 < 2; t2++) {
          const float4 rr = rv[mi * 4 + 2 * kc + t2];
          float p0 = __builtin_amdgcn_exp2f(fmaf(st[t2][mi][0], SC, rr.x));
          float p1 = __builtin_amdgcn_exp2f(fmaf(st[t2][mi][1], SC, rr.y));
          float p2 = __builtin_amdgcn_exp2f(fmaf(st[t2][mi][2], SC, rr.z));
          float p3 = __builtin_amdgcn_exp2f(fmaf(st[t2][mi][3], SC, rr.w));
          acc += (p0 + p1) + (p2 + p3);
          d[t2][0] = pkcvt(p0, p1);
          d[t2][1] = pkcvt(p2, p3);
        }
        l_lane[mi] += acc;
        // swap1: reg (kt4&1) -> lane bit5 ; swap2: bit5 -> bit4, bit4 -> reg
        const uint2v e0 = plswap32(d[0][0], d[1][0]);
        const uint2v e1 = plswap32(d[0][1], d[1][1]);
        const uint2v f0 = plswap16(e0[0], e0[1]);
        const uint2v f1 = plswap16(e1[0], e1[1]);
        union { short8 s; unsigned u[4]; } P;
        P.u[0] = f0[0]; P.u[1] = f1[0]; P.u[2] = f0[1]; P.u[3] = f1[1];
        pb[mi] = P.s;  // bf16 j=0..7 = key kc*32 + quad*8 + j, col q=n16
      }
      // ---- prefetch rel(kt+1) once per iter (rv fully dead after kc=1 exp)
      if (kc == 1 && dodma) {
#pragma unroll
        for (int j = 0; j < 8; j++) rv[j] = rp[j * 64];
        rp += 2048;
      }
      // ---- PV chunk: O^T += V^T . P^T  (B-frag straight from registers)
      short8 va[4];
#pragma unroll
      for (int nc = 0; nc < 4; nc++)
        va[nc] = *(const short8*)(sVtB + CUR * 8192 + 2048 * nc +
                                  (kc ? vb1 : vb0));
#pragma unroll
      for (int nc = 0; nc < 4; nc++)
#pragma unroll
        for (int mi = 0; mi < 2; mi++)
          ot[nc][mi] = MFMA16(va[nc], pb[mi], ot[nc][mi]);
    }
  };

#pragma unroll 1
  for (int t = 0; t < 16; t++) {
    const bool g = (t < 15);
    step(IC<0>{}, true, g);  // kt = 2t   (DMA guard 2t<31 always true)
    step(IC<1>{}, g, g);     // kt = 2t+1
  }

  // ---- epilogue: l reduce over quads (lanes n16 / +16 / +32 / +48)
  float inv[2];
#pragma unroll
  for (int mi = 0; mi < 2; mi++) {
    float l = l_lane[mi];
    l += __shfl_xor(l, 16);
    l += __shfl_xor(l, 32);
    inv[mi] = 1.0f / l;
  }
  // sK/sVt are dead; reuse LDS as per-wave transpose scratch (needs barrier:
  // a lagging wave may still be reading sK/sVt of the final tile)
  __syncthreads();
  bf16* const sEp = (bf16*)smem + w * (32 * 72);  // 4 waves x 4608 B = 18432 B
  // transpose O^T -> [q][d] via wave-private LDS (packed b64 writes)
#pragma unroll
  for (int mi = 0; mi < 2; mi++)
#pragma unroll
    for (int nc = 0; nc < 4; nc++) {
      uint2 pk;
      pk.x = pkcvt(ot[nc][mi][0] * inv[mi], ot[nc][mi][1] * inv[mi]);
      pk.y = pkcvt(ot[nc][mi][2] * inv[mi], ot[nc][mi][3] * inv[mi]);
      *(uint2*)(&sEp[(mi * 16 + n16) * 72 + nc * 16 + quad * 4]) = pk;
    }
  // coalesced store: 32 rows x 64 d, 16B per lane
#pragma unroll
  for (int t = 0; t < 4; t++) {
    const int row = t * 8 + (lane >> 3);
    const int dcol = (lane & 7) * 8;
    const short8 vrow = *(const short8*)(&sEp[row * 72 + dcol]);
    *(short8*)(attn + (rowbase + qb + row) * 1024 + h * 64 + dcol) = vrow;
  }
}

// ---------------------------------------------------------------------------
// prep: fused weight cast + bias concat + x build (block ranges)
// ---------------------------------------------------------------------------
__global__ void prep_main(const float* __restrict__ fm, const float* __restrict__ scene,
                          const float* __restrict__ Wq, const float* __restrict__ Wk,
                          const float* __restrict__ Wv, const float* __restrict__ Wo,
                          const float* __restrict__ bq, const float* __restrict__ bk,
                          const float* __restrict__ bv, bf16* __restrict__ wW,
                          bf16* __restrict__ wWo, float* __restrict__ bC,
                          bf16* __restrict__ x) {
  const int blk = blockIdx.x;
  if (blk < 4096) {
    const int sel = blk >> 10;  // 0..3
    const int i = (((blk & 1023) * 256) + threadIdx.x) * 4;
    const float* src = (sel == 0) ? Wq : (sel == 1) ? Wk : (sel == 2) ? Wv : Wo;
    bf16* dst = (sel < 3) ? (wW + ((size_t)sel << 20) + i) : (wWo + i);
    const float4 v = *(const float4*)(src + i);
    dst[0] = __float2bfloat16(v.x);
    dst[1] = __float2bfloat16(v.y);
    dst[2] = __float2bfloat16(v.z);
    dst[3] = __float2bfloat16(v.w);
    if (blk == 0) {
      for (int z = threadIdx.x; z < 3072; z += 256)
        bC[z] = (z < 1024) ? bq[z] : (z < 2048) ? bk[z - 1024] : bv[z - 2048];
    }
  } else {
    const int bx = blk - 4096;
    const size_t i = ((size_t)bx * 256 + threadIdx.x) * 4;
    const int r = (int)(i >> 10), c = (int)(i & 1023);
    const int b = r >> 11, s = r & 2047;
    const float* src = (s < 1024)
                           ? (scene + ((size_t)b << 10) + c)
                           : (fm + (((size_t)b * 1024 + (s - 1024)) << 10) + c);
    const float4 v = *(const float4*)src;
    bf16* d = x + i;
    d[0] = __float2bfloat16(v.x);
    d[1] = __float2bfloat16(v.y);
    d[2] = __float2bfloat16(v.z);
    d[3] = __float2bfloat16(v.w);
  }
}

// rel -> S^T fragment-ordered relf (x log2e). One thread per output float4;
// components are 4 consecutive keys.
__global__ void prep_rel(const float* __restrict__ rel, float* __restrict__ relf) {
  const int idx = blockIdx.x * 256 + threadIdx.x;  // 0 .. 2^20-1
  const int lane = idx & 63;
  const int j = (idx >> 6) & 7;     // mi*4 + kt4
  const int w = (idx >> 9) & 3;
  const int kt = (idx >> 11) & 31;
  const int qt = idx >> 16;
  const int n16 = lane & 15, quad = lane >> 4;
  const int mi = j >> 2, kt4 = j & 3;
  const int qrow = qt * 128 + w * 32 + mi * 16 + n16;
  const int key = kt * 64 + kt4 * 16 + quad * 4;
  const float L2E = 1.44269504f;
  float4 v = *(const float4*)(rel + (size_t)qrow * 2048 + key);
  v.x *= L2E; v.y *= L2E; v.z *= L2E; v.w *= L2E;
  ((float4*)relf)[idx] = v;
}

// ---------------------------------------------------------------------------
extern "C" void kernel_launch(void* const* d_in, const int* in_sizes, int n_in,
                              void* d_out, int out_size, void* d_ws,
                              size_t ws_size, hipStream_t stream) {
  const float* fm    = (const float*)d_in[0];
  const float* scene = (const float*)d_in[1];
  const float* rel   = (const float*)d_in[2];
  const float* Wq    = (const float*)d_in[3];
  const float* bq    = (const float*)d_in[4];
  const float* Wk    = (const float*)d_in[5];
  const float* bk    = (const float*)d_in[6];
  const float* Wv    = (const float*)d_in[7];
  const float* bv    = (const float*)d_in[8];
  const float* Wo    = (const float*)d_in[9];
  const float* bo    = (const float*)d_in[10];
  float* out = (float*)d_out;

  char* ws = (char*)d_ws;
  bf16* x    = (bf16*)(ws);                          // 16 MB  [8192,1024]
  float* relf = (float*)(ws);                        // 16 MB  (aliases x; x dead after QKV GEMM)
  bf16* qkv  = (bf16*)(ws + (16u << 20));            // 48 MB  [8192,3072]
  bf16* attn = (bf16*)(ws + (64u << 20));            // 16 MB  [8192,1024]
  bf16* wW   = (bf16*)(ws + (80u << 20));            // 6 MB   [3072,1024] Wq|Wk|Wv rows
  bf16* wWo  = (bf16*)(ws + (86u << 20));            // 2 MB   [1024,1024]
  float* bC  = (float*)(ws + (88u << 20));           // 12 KB  bq|bk|bv

  prep_main<<<12288, 256, 0, stream>>>(fm, scene, Wq, Wk, Wv, Wo, bq, bk, bv,
                                       wW, wWo, bC, x);

  // QKV fused: [8192,1024] @ [3072,1024]^T + bC -> [8192,3072] bf16
  gemm_bt<1><<<dim3(24, 64), 256, 0, stream>>>(x, wW, bC, qkv, nullptr,
                                               8192, 3072, 1024);
  // x is dead now; build fragment-ordered rel into the same region
  prep_rel<<<4096, 256, 0, stream>>>(rel, relf);
  // attention: B*H*(S/128) = 4*16*16 = 1024 blocks
  flash_kernel<<<1024, 256, 0, stream>>>(qkv, relf, attn);
  // output projection: [8192,1024] @ [1024,1024]^T + bo -> f32 out
  gemm_bt<0><<<dim3(8, 64), 256, 0, stream>>>(attn, wWo, bo, nullptr, out,
                                              8192, 1024, 1024);
}

// Round 6
// 311.091 us; speedup vs baseline: 1.2391x; 1.0685x over previous
//
#include <hip/hip_runtime.h>
#include <hip/hip_bf16.h>
#include <cstdint>

// Problem constants: B=4, N=1024, F=1024, H=16, D=64, S=2N=2048.
typedef __hip_bfloat16 bf16;
typedef __attribute__((ext_vector_type(8))) short short8;   // 8 x bf16 (4 VGPRs)
typedef __attribute__((ext_vector_type(4))) float f32x4;
typedef __attribute__((ext_vector_type(2))) unsigned int uint2v;

#define MFMA16(a, b, c) __builtin_amdgcn_mfma_f32_16x16x32_bf16((a), (b), (c), 0, 0, 0)

__device__ __forceinline__ void gl2lds16(const void* g, void* l) {
  // async global->LDS, 16B/lane; LDS dest = wave-uniform base + lane*16
  __builtin_amdgcn_global_load_lds(
      (const __attribute__((address_space(1))) unsigned int*)g,
      (__attribute__((address_space(3))) unsigned int*)l,
      16, 0, 0);
}

// pack two f32 -> bf16x2 in ONE VALU op (RNE). lo16 = bf16(a), hi16 = bf16(b).
__device__ __forceinline__ unsigned int pkcvt(float a, float b) {
  unsigned int r;
  asm("v_cvt_pk_bf16_f32 %0, %1, %2" : "=v"(r) : "v"(a), "v"(b));
  return r;
}

// Collect-swap across lane bit 5: r[0] = values from lanes bit5==0 of {a,b}
// (lane bit5 encodes source reg), r[1] = values from lanes bit5==1.
__device__ __forceinline__ uint2v plswap32(unsigned a, unsigned b) {
#if __has_builtin(__builtin_amdgcn_permlane32_swap)
  return __builtin_amdgcn_permlane32_swap(a, b, false, false);
#else
  const unsigned ax = __shfl_xor((int)a, 32), bx = __shfl_xor((int)b, 32);
  const bool hi = (threadIdx.x & 32) != 0;
  uint2v r;
  r[0] = hi ? bx : a;
  r[1] = hi ? b : ax;
  return r;
#endif
}

// Collect-swap across lane bit 4 (16-lane rows), same collect semantics.
__device__ __forceinline__ uint2v plswap16(unsigned a, unsigned b) {
#if __has_builtin(__builtin_amdgcn_permlane16_swap)
  return __builtin_amdgcn_permlane16_swap(a, b, false, false);
#else
  const unsigned ax = __shfl_xor((int)a, 16), bx = __shfl_xor((int)b, 16);
  const bool hi = (threadIdx.x & 16) != 0;
  uint2v r;
  r[0] = hi ? bx : a;
  r[1] = hi ? b : ax;
  return r;
#endif
}

template <int V> struct IC { static constexpr int value = V; };

// ---------------------------------------------------------------------------
// C[M,N] = A[M,K] @ Bt[N,K]^T + bias   (all bf16 in, fp32 accum)
// v10: BK=64 (half the barrier rounds of BK=32; m233: 2-phase critical path is
// stage+vmcnt+barrier) + both-sides XOR swizzle: LDS [row][64] with element
// (row, c') holding X[row][c' ^ ((row&7)<<3)] (pre-swizzled global source for
// gl2lds; reads at byte ^ ((n16&7)<<4)) -> 2-way banks = free (m136).
// LDS 32 KB; occupancy still VGPR-bound at 3 blocks/CU (unchanged).
// 128x128 tile, 256 threads (4 waves in 2x2), 16x16x32 bf16 MFMA.
// ---------------------------------------------------------------------------
template <int WRITE_BF16>
__global__ __launch_bounds__(256) void gemm_bt(
    const bf16* __restrict__ A, const bf16* __restrict__ Bt,
    const float* __restrict__ bias, bf16* __restrict__ outb,
    float* __restrict__ outf, int M, int N, int K) {
  __shared__ bf16 sA[128 * 64];
  __shared__ bf16 sB[128 * 64];
  const int tid = threadIdx.x, w = tid >> 6, lane = tid & 63;
  const int n16 = lane & 15, quad = lane >> 4;
  const int mBase = blockIdx.y * 128, nBase = blockIdx.x * 128;
  const int wr = w >> 1, wc = w & 1;  // wave covers rows wr*64.., cols wc*64..

  f32x4 acc[4][4];
#pragma unroll
  for (int mi = 0; mi < 4; mi++)
#pragma unroll
    for (int ni = 0; ni < 4; ni++) acc[mi][ni] = (f32x4){0.f, 0.f, 0.f, 0.f};

  // DMA sources with the inverse swizzle baked into the column
  const bf16* ag[4];
  const bf16* bg[4];
#pragma unroll
  for (int i = 0; i < 4; i++) {
    const int e = (i * 256 + tid) * 8;       // element in 128x64 tile
    const int row = e >> 6, c0 = e & 63;     // c0 multiple of 8
    const int col = c0 ^ ((row & 7) << 3);   // stays in [0,64), 8-contig
    ag[i] = A + (size_t)(mBase + row) * K + col;
    bg[i] = Bt + (size_t)(nBase + row) * K + col;
  }
  // swizzled fragment-read byte bases: row r = w*64+t*16+n16 -> (r&7)=n16&7
  const int u = (quad * 16) ^ ((n16 & 7) << 4);
  const int a0 = (wr * 64 + n16) * 128 + u;
  const int b0 = (wc * 64 + n16) * 128 + u;
  const char* const sAB = (const char*)sA;
  const char* const sBB = (const char*)sB;

  for (int k0 = 0; k0 < K; k0 += 64) {
    __syncthreads();  // previous iteration's frag reads must finish
#pragma unroll
    for (int i = 0; i < 4; i++) {
      gl2lds16(ag[i] + k0, sA + i * 2048 + w * 512);
      gl2lds16(bg[i] + k0, sB + i * 2048 + w * 512);
    }
    __syncthreads();  // drains vmcnt (global_load_lds) + makes LDS visible

#pragma unroll
    for (int kk = 0; kk < 2; kk++) {
      short8 af[4], bfg[4];
#pragma unroll
      for (int t = 0; t < 4; t++) {
        af[t] = *(const short8*)(sAB + (a0 ^ (kk << 6)) + t * 2048);
        bfg[t] = *(const short8*)(sBB + (b0 ^ (kk << 6)) + t * 2048);
      }
#pragma unroll
      for (int mi = 0; mi < 4; mi++)
#pragma unroll
        for (int ni = 0; ni < 4; ni++)
          acc[mi][ni] = MFMA16(af[mi], bfg[ni], acc[mi][ni]);
    }
  }

  // Epilogue. C/D layout: col = lane&15, row = quad*4 + reg  [verified m89/m91]
#pragma unroll
  for (int mi = 0; mi < 4; mi++)
#pragma unroll
    for (int ni = 0; ni < 4; ni++)
#pragma unroll
      for (int r = 0; r < 4; r++) {
        const int row = mBase + wr * 64 + mi * 16 + quad * 4 + r;
        const int col = nBase + wc * 64 + ni * 16 + n16;
        const float v = acc[mi][ni][r] + bias[col];
        if (WRITE_BF16)
          outb[(size_t)row * N + col] = __float2bfloat16(v);
        else
          outf[(size_t)row * N + col] = v;
      }
}

// ---------------------------------------------------------------------------
// Flash attention v10. v9 post-mortem: bank conflicts 8.5M->4.4M (sVt swizzle
// worked); remaining 4.4M are the K-reads (64-B sK rows -> 8-way). FETCH rose
// 167->262 MB: bh-grouped XCD map made each XCD read all 16 MB of rel (>4MB L2).
// Changes:
//  - sK re-laid out [key][64 d] + both-sides XOR swizzle (pre-swizzled DMA
//    source col ^ ((key&7)<<3); reads at byte ^ ((n16&7)<<4)) -> 2-way = free
//  - XCD map back to identity (v7's 167 MB fetch behavior)
//  - rel loads split over two base pointers (all offsets fold to imm <4096)
// Kept from v9: sVt swizzle, v_perm V-pack, cvt_pk, kt x2 unroll, permlane P^T.
// ---------------------------------------------------------------------------
__global__ __launch_bounds__(256) void flash_kernel(
    const bf16* __restrict__ qkv, const float* __restrict__ relf,
    bf16* __restrict__ attn) {
  constexpr int S = 2048, R3 = 3072;
  // sK = 2 x [64][64] bf16 swizzled (16384 B) + sVt = 2 x [64][64] swizzled
  __shared__ __align__(16) char smem[32768];
  bf16* const sK = (bf16*)smem;       // [buf][key][64] 128 B rows, XOR-swizzled
  char* const sVtB = smem + 16384;    // [buf][d][key] 128 B rows, XOR-swizzled

  const int tid = threadIdx.x, w = tid >> 6, lane = tid & 63;
  const int n16 = lane & 15, quad = lane >> 4;
  const int qt = blockIdx.x & 15;    // identity map: 16 q-tiles of 128
  const int bh = blockIdx.x >> 4;
  const int h = bh & 15, b = bh >> 4;
  const int qb = qt * 128 + w * 32;  // this wave's first q row (within S)
  const size_t rowbase = (size_t)b * S;
  const float SC = 0.125f * 1.44269504f;  // (1/sqrt(D)) * log2(e)
  const size_t TADV = (size_t)64 * R3;    // advance one key-tile

  // Q B-frags [mi][dchunk]: lane holds B[n=n16][k=quad*8+j]
  short8 qf[2][2];
#pragma unroll
  for (int mi = 0; mi < 2; mi++) {
    const bf16* qp = qkv + (rowbase + qb + mi * 16 + n16) * R3 + h * 64;
#pragma unroll
    for (int c = 0; c < 2; c++) qf[mi][c] = *(const short8*)(qp + c * 32 + quad * 8);
  }

  f32x4 ot[4][2];  // O^T accum: [d-tile nc][q-tile mi]; row=d, col=q
#pragma unroll
  for (int nc = 0; nc < 4; nc++)
#pragma unroll
    for (int mi = 0; mi < 2; mi++) ot[nc][mi] = (f32x4){0.f, 0.f, 0.f, 0.f};
  float l_lane[2] = {0.f, 0.f};

  // ---- K-DMA source pointers (tile 0) with inverse swizzle baked in
  const bf16* kg0;
  const bf16* kg1;
  {
    const int e0 = tid * 8;
    const int e1 = (256 + tid) * 8;
    const int k0r = e0 >> 6, c00 = e0 & 63;
    const int k1r = e1 >> 6, c01 = e1 & 63;
    kg0 = qkv + (rowbase + k0r) * R3 + 1024 + h * 64 + (c00 ^ ((k0r & 7) << 3));
    kg1 = qkv + (rowbase + k1r) * R3 + 1024 + h * 64 + (c01 ^ ((k1r & 7) << 3));
  }
  const int kldsoff = w * 512;  // elements; + i*2048 + buf*4096

  // ---- swizzled K read bases (bytes): key row = kt4*16+n16, (key&7)=n16&7
  const int kb0 = n16 * 128 + ((quad * 16) ^ ((n16 & 7) << 4));  // c=0
  const int kb1 = kb0 ^ 64;                                      // c=1
  const char* const sKB = (const char*)sK;

  // ---- V staging mapping: thread -> (key pair, d octet)
  const int kp = lane & 31;                  // keys 2kp, 2kp+1
  const int vd0 = w * 16 + (lane >> 5) * 8;  // 8 d values (multiple of 8)
  const int kp4 = kp * 4;                    // unswizzled in-row byte of key pair
  const bf16* vp = qkv + (rowbase + 2 * kp) * R3 + 2048 + h * 64 + vd0;

  // ---- sVt swizzled read bases (per-lane, once): row d = nc*16+n16;
  // in-row byte u = 64*kc + 16*quad, stored at u ^ ((d&7)<<4) = u ^ ((n16&7)<<4)
  const int vb0 = 128 * n16 + ((16 * quad) ^ ((n16 & 7) << 4));  // kc=0
  const int vb1 = vb0 ^ 64;                                      // kc=1

  short8 v0, v1;
  // stage V^T tile from regs into sVt[BUF] (v_perm pack + swizzled dword writes)
  auto vstage = [&](int bufbyte) {
    const unsigned* a1 = (const unsigned*)&v1;
    const unsigned* a0 = (const unsigned*)&v0;
#pragma unroll
    for (int j = 0; j < 4; j++) {
      // u_even = {v1[2j].lo16 : v0[2j].lo16}, u_odd from hi16 halves
      const unsigned lo = __builtin_amdgcn_perm(a1[j], a0[j], 0x05040100u);
      const unsigned hi = __builtin_amdgcn_perm(a1[j], a0[j], 0x07060302u);
      *(unsigned*)(sVtB + bufbyte + 128 * (vd0 + 2 * j) + (kp4 ^ ((2 * j) << 4))) = lo;
      *(unsigned*)(sVtB + bufbyte + 128 * (vd0 + 2 * j + 1) + (kp4 ^ ((2 * j + 1) << 4))) = hi;
    }
  };

  // ---- prologue: DMA K(0) -> sK buf0; V(0) -> sVt buf0; regs V(1), rel(0)
  gl2lds16(kg0, sK + kldsoff);
  gl2lds16(kg1, sK + kldsoff + 2048);
  kg0 += TADV;
  kg1 += TADV;

  v0 = *(const short8*)vp;
  v1 = *(const short8*)(vp + R3);
  vstage(0);
  vp += TADV;
  v0 = *(const short8*)vp;          // V(1) into regs
  v1 = *(const short8*)(vp + R3);
  vp += TADV;                       // -> tile 2

  float4 rv[8];
  const float4* rpA = (const float4*)relf + (size_t)(qt * 32) * 2048 + w * 512 + lane;
  const float4* rpB = rpA + 256;
#pragma unroll
  for (int j = 0; j < 4; j++) {
    rv[j] = rpA[j * 64];
    rv[4 + j] = rpB[j * 64];
  }
  rpA += 2048;
  rpB += 2048;

  // one kt iteration; CUR is compile-time (static LDS offsets)
  auto step = [&](auto curc, bool dodma, bool dovpf) {
    constexpr int CUR = decltype(curc)::value;
    constexpr int NXT = CUR ^ 1;
    __syncthreads();  // drains DMA(kt) + V^T(kt) visible + prev readers done

    if (dodma) {
      gl2lds16(kg0, sK + NXT * 4096 + kldsoff);
      kg0 += TADV;
      gl2lds16(kg1, sK + NXT * 4096 + kldsoff + 2048);
      kg1 += TADV;
      vstage(NXT * 8192);
    }

#pragma unroll
    for (int kc = 0; kc < 2; kc++) {
      // ---- S^T chunk = K.Q^T for kt4 in {2kc, 2kc+1}: row=key, col=q
      f32x4 st[2][2];  // [t2][mi]
#pragma unroll
      for (int t2 = 0; t2 < 2; t2++) {
        const int kt4 = 2 * kc + t2;
        short8 kf[2];
        kf[0] = *(const short8*)(sKB + CUR * 8192 + kt4 * 2048 + kb0);
        kf[1] = *(const short8*)(sKB + CUR * 8192 + kt4 * 2048 + kb1);
#pragma unroll
        for (int mi = 0; mi < 2; mi++) {
          f32x4 z = (f32x4){0.f, 0.f, 0.f, 0.f};
          z = MFMA16(kf[0], qf[mi][0], z);
          z = MFMA16(kf[1], qf[mi][1], z);
          st[t2][mi] = z;
        }
      }
      // ---- prefetch V(kt+2) regs once per iter (hides under exp/PV)
      if (kc == 0 && dovpf) {
        v0 = *(const short8*)vp;
        v1 = *(const short8*)(vp + R3);
        vp += TADV;
      }
      // ---- p = 2^(s*SC + rel'), cvt_pk to bf16, permlane into PV B-frag
      short8 pb[2];  // [mi]
#pragma unroll
      for (int mi = 0; mi < 2; mi++) {
        float acc = 0.f;
        unsigned d[2][2];  // [t2][h]; dword = keys (2kc+t2)*16+quad*4+2h,+2h+1
#pragma unroll
        for (int t2 = 0; t2 < 2; t2++) {
          const float4 rr = rv[mi * 4 + 2 * kc + t2];
          float p0 = __builtin_amdgcn_exp2f(fmaf(st[t2][mi][0], SC, rr.x));
          float p1 = __builtin_amdgcn_exp2f(fmaf(st[t2][mi][1], SC, rr.y));
          float p2 = __builtin_amdgcn_exp2f(fmaf(st[t2][mi][2], SC, rr.z));
          float p3 = __builtin_amdgcn_exp2f(fmaf(st[t2][mi][3], SC, rr.w));
          acc += (p0 + p1) + (p2 + p3);
          d[t2][0] = pkcvt(p0, p1);
          d[t2][1] = pkcvt(p2, p3);
        }
        l_lane[mi] += acc;
        // swap1: reg (kt4&1) -> lane bit5 ; swap2: bit5 -> bit4, bit4 -> reg
        const uint2v e0 = plswap32(d[0][0], d[1][0]);
        const uint2v e1 = plswap32(d[0][1], d[1][1]);
        const uint2v f0 = plswap16(e0[0], e0[1]);
        const uint2v f1 = plswap16(e1[0], e1[1]);
        union { short8 s; unsigned u[4]; } P;
        P.u[0] = f0[0]; P.u[1] = f1[0]; P.u[2] = f0[1]; P.u[3] = f1[1];
        pb[mi] = P.s;  // bf16 j=0..7 = key kc*32 + quad*8 + j, col q=n16
      }
      // ---- prefetch rel(kt+1) once per iter (rv fully dead after kc=1 exp)
      if (kc == 1 && dodma) {
#pragma unroll
        for (int j = 0; j < 4; j++) {
          rv[j] = rpA[j * 64];
          rv[4 + j] = rpB[j * 64];
        }
        rpA += 2048;
        rpB += 2048;
      }
      // ---- PV chunk: O^T += V^T . P^T  (B-frag straight from registers)
      short8 va[4];
#pragma unroll
      for (int nc = 0; nc < 4; nc++)
        va[nc] = *(const short8*)(sVtB + CUR * 8192 + 2048 * nc +
                                  (kc ? vb1 : vb0));
#pragma unroll
      for (int nc = 0; nc < 4; nc++)
#pragma unroll
        for (int mi = 0; mi < 2; mi++)
          ot[nc][mi] = MFMA16(va[nc], pb[mi], ot[nc][mi]);
    }
  };

#pragma unroll 1
  for (int t = 0; t < 16; t++) {
    const bool g = (t < 15);
    step(IC<0>{}, true, g);  // kt = 2t   (DMA guard 2t<31 always true)
    step(IC<1>{}, g, g);     // kt = 2t+1
  }

  // ---- epilogue: l reduce over quads (lanes n16 / +16 / +32 / +48)
  float inv[2];
#pragma unroll
  for (int mi = 0; mi < 2; mi++) {
    float l = l_lane[mi];
    l += __shfl_xor(l, 16);
    l += __shfl_xor(l, 32);
    inv[mi] = 1.0f / l;
  }
  // sK/sVt are dead; reuse LDS as per-wave transpose scratch (needs barrier:
  // a lagging wave may still be reading sK/sVt of the final tile)
  __syncthreads();
  bf16* const sEp = (bf16*)smem + w * (32 * 72);  // 4 waves x 4608 B = 18432 B
  // transpose O^T -> [q][d] via wave-private LDS (packed b64 writes)
#pragma unroll
  for (int mi = 0; mi < 2; mi++)
#pragma unroll
    for (int nc = 0; nc < 4; nc++) {
      uint2 pk;
      pk.x = pkcvt(ot[nc][mi][0] * inv[mi], ot[nc][mi][1] * inv[mi]);
      pk.y = pkcvt(ot[nc][mi][2] * inv[mi], ot[nc][mi][3] * inv[mi]);
      *(uint2*)(&sEp[(mi * 16 + n16) * 72 + nc * 16 + quad * 4]) = pk;
    }
  // coalesced store: 32 rows x 64 d, 16B per lane
#pragma unroll
  for (int t = 0; t < 4; t++) {
    const int row = t * 8 + (lane >> 3);
    const int dcol = (lane & 7) * 8;
    const short8 vrow = *(const short8*)(&sEp[row * 72 + dcol]);
    *(short8*)(attn + (rowbase + qb + row) * 1024 + h * 64 + dcol) = vrow;
  }
}

// ---------------------------------------------------------------------------
// prep: fused weight cast + bias concat + x build (block ranges)
// ---------------------------------------------------------------------------
__global__ void prep_main(const float* __restrict__ fm, const float* __restrict__ scene,
                          const float* __restrict__ Wq, const float* __restrict__ Wk,
                          const float* __restrict__ Wv, const float* __restrict__ Wo,
                          const float* __restrict__ bq, const float* __restrict__ bk,
                          const float* __restrict__ bv, bf16* __restrict__ wW,
                          bf16* __restrict__ wWo, float* __restrict__ bC,
                          bf16* __restrict__ x) {
  const int blk = blockIdx.x;
  if (blk < 4096) {
    const int sel = blk >> 10;  // 0..3
    const int i = (((blk & 1023) * 256) + threadIdx.x) * 4;
    const float* src = (sel == 0) ? Wq : (sel == 1) ? Wk : (sel == 2) ? Wv : Wo;
    bf16* dst = (sel < 3) ? (wW + ((size_t)sel << 20) + i) : (wWo + i);
    const float4 v = *(const float4*)(src + i);
    dst[0] = __float2bfloat16(v.x);
    dst[1] = __float2bfloat16(v.y);
    dst[2] = __float2bfloat16(v.z);
    dst[3] = __float2bfloat16(v.w);
    if (blk == 0) {
      for (int z = threadIdx.x; z < 3072; z += 256)
        bC[z] = (z < 1024) ? bq[z] : (z < 2048) ? bk[z - 1024] : bv[z - 2048];
    }
  } else {
    const int bx = blk - 4096;
    const size_t i = ((size_t)bx * 256 + threadIdx.x) * 4;
    const int r = (int)(i >> 10), c = (int)(i & 1023);
    const int b = r >> 11, s = r & 2047;
    const float* src = (s < 1024)
                           ? (scene + ((size_t)b << 10) + c)
                           : (fm + (((size_t)b * 1024 + (s - 1024)) << 10) + c);
    const float4 v = *(const float4*)src;
    bf16* d = x + i;
    d[0] = __float2bfloat16(v.x);
    d[1] = __float2bfloat16(v.y);
    d[2] = __float2bfloat16(v.z);
    d[3] = __float2bfloat16(v.w);
  }
}

// rel -> S^T fragment-ordered relf (x log2e). One thread per output float4;
// components are 4 consecutive keys.
__global__ void prep_rel(const float* __restrict__ rel, float* __restrict__ relf) {
  const int idx = blockIdx.x * 256 + threadIdx.x;  // 0 .. 2^20-1
  const int lane = idx & 63;
  const int j = (idx >> 6) & 7;     // mi*4 + kt4
  const int w = (idx >> 9) & 3;
  const int kt = (idx >> 11) & 31;
  const int qt = idx >> 16;
  const int n16 = lane & 15, quad = lane >> 4;
  const int mi = j >> 2, kt4 = j & 3;
  const int qrow = qt * 128 + w * 32 + mi * 16 + n16;
  const int key = kt * 64 + kt4 * 16 + quad * 4;
  const float L2E = 1.44269504f;
  float4 v = *(const float4*)(rel + (size_t)qrow * 2048 + key);
  v.x *= L2E; v.y *= L2E; v.z *= L2E; v.w *= L2E;
  ((float4*)relf)[idx] = v;
}

// ---------------------------------------------------------------------------
extern "C" void kernel_launch(void* const* d_in, const int* in_sizes, int n_in,
                              void* d_out, int out_size, void* d_ws,
                              size_t ws_size, hipStream_t stream) {
  const float* fm    = (const float*)d_in[0];
  const float* scene = (const float*)d_in[1];
  const float* rel   = (const float*)d_in[2];
  const float* Wq    = (const float*)d_in[3];
  const float* bq    = (const float*)d_in[4];
  const float* Wk    = (const float*)d_in[5];
  const float* bk    = (const float*)d_in[6];
  const float* Wv    = (const float*)d_in[7];
  const float* bv    = (const float*)d_in[8];
  const float* Wo    = (const float*)d_in[9];
  const float* bo    = (const float*)d_in[10];
  float* out = (float*)d_out;

  char* ws = (char*)d_ws;
  bf16* x    = (bf16*)(ws);                          // 16 MB  [8192,1024]
  float* relf = (float*)(ws);                        // 16 MB  (aliases x; x dead after QKV GEMM)
  bf16* qkv  = (bf16*)(ws + (16u << 20));            // 48 MB  [8192,3072]
  bf16* attn = (bf16*)(ws + (64u << 20));            // 16 MB  [8192,1024]
  bf16* wW   = (bf16*)(ws + (80u << 20));            // 6 MB   [3072,1024] Wq|Wk|Wv rows
  bf16* wWo  = (bf16*)(ws + (86u << 20));            // 2 MB   [1024,1024]
  float* bC  = (float*)(ws + (88u << 20));           // 12 KB  bq|bk|bv

  prep_main<<<12288, 256, 0, stream>>>(fm, scene, Wq, Wk, Wv, Wo, bq, bk, bv,
                                       wW, wWo, bC, x);

  // QKV fused: [8192,1024] @ [3072,1024]^T + bC -> [8192,3072] bf16
  gemm_bt<1><<<dim3(24, 64), 256, 0, stream>>>(x, wW, bC, qkv, nullptr,
                                               8192, 3072, 1024);
  // x is dead now; build fragment-ordered rel into the same region
  prep_rel<<<4096, 256, 0, stream>>>(rel, relf);
  // attention: B*H*(S/128) = 4*16*16 = 1024 blocks
  flash_kernel<<<1024, 256, 0, stream>>>(qkv, relf, attn);
  // output projection: [8192,1024] @ [1024,1024]^T + bo -> f32 out
  gemm_bt<0><<<dim3(8, 64), 256, 0, stream>>>(attn, wWo, bo, nullptr, out,
                                              8192, 1024, 1024);
}